// Round 9
// baseline (560.479 us; speedup 1.0000x reference)
//
#include <hip/hip_runtime.h>

// ReadInAttention — single persistent kernel, 8 phases, atomic grid barriers.
// R9: read-only barrier polling (no RMW spam), ds_read_b128 A-frags in gcore,
// phase-6 LDS group padding (bank conflicts), s_sleep backoff.

#define DD 768
#define CDIM 384
#define NH 8
#define HD 64
#define INNER 512
#define VV 256
#define GRID 448

__device__ __forceinline__ void fma4(float4& a, float s, const float4& b) {
  a.x += s * b.x; a.y += s * b.y; a.z += s * b.z; a.w += s * b.w;
}

// A0: LDS, rows at stride lda (multiple of 4, 16B-aligned base). B: global.
template <int K, int NS>
__device__ __forceinline__ void gcore(const float* __restrict__ A0, int lda,
                                      const float* __restrict__ Bp,
                                      float4& a0, float4& a1, float4& a2,
                                      float4& a3) {
  float4 b0[8], b1[8];
#pragma unroll
  for (int i = 0; i < 8; i++) b0[i] = *(const float4*)(Bp + (size_t)i * NS);
  const float* Bq = Bp + (size_t)8 * NS;
#pragma unroll 1
  for (int kk = 0; kk < K; kk += 16) {
#pragma unroll
    for (int i = 0; i < 8; i++) b1[i] = *(const float4*)(Bq + (size_t)i * NS);
    Bq += (size_t)8 * NS;
#pragma unroll
    for (int c = 0; c < 2; c++) {
      int kb = kk + c * 4;
      float4 f0 = *(const float4*)(A0 + kb);
      float4 f1 = *(const float4*)(A0 + lda + kb);
      float4 f2 = *(const float4*)(A0 + 2 * lda + kb);
      float4 f3 = *(const float4*)(A0 + 3 * lda + kb);
      float4 bv;
      bv = b0[c*4+0]; fma4(a0,f0.x,bv); fma4(a1,f1.x,bv); fma4(a2,f2.x,bv); fma4(a3,f3.x,bv);
      bv = b0[c*4+1]; fma4(a0,f0.y,bv); fma4(a1,f1.y,bv); fma4(a2,f2.y,bv); fma4(a3,f3.y,bv);
      bv = b0[c*4+2]; fma4(a0,f0.z,bv); fma4(a1,f1.z,bv); fma4(a2,f2.z,bv); fma4(a3,f3.z,bv);
      bv = b0[c*4+3]; fma4(a0,f0.w,bv); fma4(a1,f1.w,bv); fma4(a2,f2.w,bv); fma4(a3,f3.w,bv);
    }
    if (kk + 16 < K) {
#pragma unroll
      for (int i = 0; i < 8; i++) b0[i] = *(const float4*)(Bq + (size_t)i * NS);
      Bq += (size_t)8 * NS;
    }
#pragma unroll
    for (int c = 0; c < 2; c++) {
      int kb = kk + 8 + c * 4;
      float4 f0 = *(const float4*)(A0 + kb);
      float4 f1 = *(const float4*)(A0 + lda + kb);
      float4 f2 = *(const float4*)(A0 + 2 * lda + kb);
      float4 f3 = *(const float4*)(A0 + 3 * lda + kb);
      float4 bv;
      bv = b1[c*4+0]; fma4(a0,f0.x,bv); fma4(a1,f1.x,bv); fma4(a2,f2.x,bv); fma4(a3,f3.x,bv);
      bv = b1[c*4+1]; fma4(a0,f0.y,bv); fma4(a1,f1.y,bv); fma4(a2,f2.y,bv); fma4(a3,f3.y,bv);
      bv = b1[c*4+2]; fma4(a0,f0.z,bv); fma4(a1,f1.z,bv); fma4(a2,f2.z,bv); fma4(a3,f3.z,bv);
      bv = b1[c*4+3]; fma4(a0,f0.w,bv); fma4(a1,f1.w,bv); fma4(a2,f2.w,bv); fma4(a3,f3.w,bv);
    }
  }
}

__device__ __forceinline__ void gbar(unsigned* bar, unsigned target) {
  __syncthreads();
  if (threadIdx.x == 0) {
    __threadfence();          // release prior writes
    atomicAdd(bar, 1u);       // fire-and-forget arrival
    while (__hip_atomic_load(bar, __ATOMIC_RELAXED,
                             __HIP_MEMORY_SCOPE_AGENT) < target)
      __builtin_amdgcn_s_sleep(16);
    __threadfence();          // acquire
  }
  __syncthreads();
}

__global__ __launch_bounds__(256, 2) void k_all(
    const float* __restrict__ rs, const float* __restrict__ codes,
    const float* __restrict__ ss, const float* __restrict__ g_r,
    const float* __restrict__ b_r, const float* __restrict__ g_s,
    const float* __restrict__ b_s, const float* __restrict__ Wq,
    const float* __restrict__ bq, const float* __restrict__ Wmq,
    const float* __restrict__ Wk, const float* __restrict__ bk,
    const float* __restrict__ Wmk, const float* __restrict__ Wv,
    const float* __restrict__ bvv, const float* __restrict__ Wmv,
    const float* __restrict__ We, const float* __restrict__ be,
    const float* __restrict__ Wme, const float* __restrict__ gamma,
    float* __restrict__ w, float* __restrict__ outp, unsigned* __restrict__ bar) {
  __shared__ __align__(16) float SB[6400];
  float* s_ln = w;                  // 786432   (P1 -> P5)
  float* r_ln = w + 786432;         // 196608   (P1 -> P2)
  float* WkT  = w + 983040;         // 393216   (P1 -> P3)
  float* qp   = w + 1376256;        // 524288   (P2 -> P3, 4 partials)
  float* sT   = w + 1900544;        // 786432   (P2 -> P4)
  float* cp   = w + 2686976;        // 720896   (P1 -> P7) [m][2816]
  float* qbk  = w + 3407872;        // 2048     (P3 -> P5)
  float* qm   = w + 3409920;        // 1572864  (P3 -> P4)
  float* scp  = w + 4982784;        // 2097152  (P4 -> P5, 4 partials)
  float* wsm  = qm;                 // alias (P5 -> P6)
  float* mmp  = r_ln;               // alias r_ln+WkT+qp (P6 -> P7, 8 partials)
  float* op   = scp;                // alias (P7 -> P8, 8 partials)

  int t = threadIdx.x;
  unsigned target = 0;

  // ================= Phase 1: code GEMM | WkT | LN =================
  for (int tile = blockIdx.x; tile < 1552; tile += GRID) {
    if (tile < 176) {
      int nc = tile % 11, mb = tile / 11;
      int base = nc * 256;
      const float* W; int N, colW;
      if (base < 768)       { W = Wmq; N = DD;    colW = base; }
      else if (base < 1536) { W = Wmk; N = DD;    colW = base - 768; }
      else if (base < 2304) { W = Wmv; N = DD;    colW = base - 1536; }
      else                  { W = Wme; N = INNER; colW = base - 2304; }
      int m0 = mb * 16;
#pragma unroll
      for (int p = 0; p < 24; p++) {
        int idx = p * 256 + t, r = idx / 384, k = idx % 384;
        SB[idx] = codes[(size_t)(m0 + r) * CDIM + k];
      }
      __syncthreads();
      int kl = t & 63, wid = t >> 6;
      const float* A0 = SB + (wid * 4) * 384;
      float4 a0 = {0,0,0,0}, a1 = {0,0,0,0}, a2 = {0,0,0,0}, a3 = {0,0,0,0};
      if (N == DD)
        gcore<384, DD>(A0, 384, W + colW + 4 * kl, a0, a1, a2, a3);
      else
        gcore<384, INNER>(A0, 384, W + colW + 4 * kl, a0, a1, a2, a3);
      int m = m0 + wid * 4, gcol = base + 4 * kl;
      *(float4*)(cp + (size_t)m * 2816 + gcol) = a0;
      *(float4*)(cp + (size_t)(m + 1) * 2816 + gcol) = a1;
      *(float4*)(cp + (size_t)(m + 2) * 2816 + gcol) = a2;
      *(float4*)(cp + (size_t)(m + 3) * 2816 + gcol) = a3;
    } else if (tile < 272) {
      int tid = tile - 176;
      int d0 = (tid >> 3) * 64, c0 = (tid & 7) * 64;
      int j = t & 63, i0 = t >> 6;
#pragma unroll
      for (int p = 0; p < 16; p++) {
        int i = p * 4 + i0;
        SB[i * 65 + j] = Wk[(size_t)(d0 + i) * INNER + c0 + j];
      }
      __syncthreads();
#pragma unroll
      for (int p = 0; p < 16; p++) {
        int i = p * 4 + i0;
        WkT[(size_t)(c0 + i) * DD + d0 + j] = SB[j * 65 + i];
      }
    } else {
      int rr = tile - 272;
      const float *x, *g, *bb; float* y; int r;
      if (rr < 1024) { x = ss; g = g_s; bb = b_s; y = s_ln; r = rr; }
      else           { x = rs; g = g_r; bb = b_r; y = r_ln; r = rr - 1024; }
      const float* xr = x + (size_t)r * DD;
      float v0 = xr[t], v1 = xr[t + 256], v2 = xr[t + 512];
      float s = v0 + v1 + v2, sq = v0 * v0 + v1 * v1 + v2 * v2;
      for (int o = 32; o > 0; o >>= 1) {
        s += __shfl_down(s, o, 64); sq += __shfl_down(sq, o, 64);
      }
      int wid = t >> 6, lane = t & 63;
      if (lane == 0) { SB[wid] = s; SB[wid + 4] = sq; }
      __syncthreads();
      float sum = SB[0] + SB[1] + SB[2] + SB[3];
      float ssq = SB[4] + SB[5] + SB[6] + SB[7];
      float mu = sum * (1.0f / 768.0f);
      float var = ssq * (1.0f / 768.0f) - mu * mu;
      float rstd = rsqrtf(var + 1e-5f);
      float* yr = y + (size_t)r * DD;
      yr[t]       = (v0 - mu) * rstd * g[t]       + bb[t];
      yr[t + 256] = (v1 - mu) * rstd * g[t + 256] + bb[t + 256];
      yr[t + 512] = (v2 - mu) * rstd * g[t + 512] + bb[t + 512];
    }
    __syncthreads();
  }
  target += GRID; gbar(bar, target);

  // ================= Phase 2: q partial (128) | sT (192) =================
  for (int tile = blockIdx.x; tile < 320; tile += GRID) {
    if (tile < 128) {
      int ks = tile & 3, t2 = tile >> 2, nc = t2 & 1, mb = t2 >> 1;
      int m0 = mb * 16, col0 = nc * 256, k0 = ks * 192;
#pragma unroll
      for (int p = 0; p < 12; p++) {
        int idx = p * 256 + t, r = idx / 192, k = idx % 192;
        int d = k0 + k;
        float mqv = cp[(size_t)(m0 + r) * 2816 + d] + 1.0f;
        SB[idx] = r_ln[(size_t)(m0 + r) * DD + d] * mqv;
      }
      __syncthreads();
      int kl = t & 63, wid = t >> 6;
      int col = col0 + 4 * kl;
      const float* A0 = SB + (wid * 4) * 192;
      float4 a0 = {0,0,0,0}, a1 = {0,0,0,0}, a2 = {0,0,0,0}, a3 = {0,0,0,0};
      gcore<192, INNER>(A0, 192, Wq + (size_t)k0 * INNER + col, a0, a1, a2, a3);
      int m = m0 + wid * 4;
      float* dst = qp + (size_t)ks * (256 * INNER);
      *(float4*)(dst + (size_t)m * INNER + col) = a0;
      *(float4*)(dst + (size_t)(m + 1) * INNER + col) = a1;
      *(float4*)(dst + (size_t)(m + 2) * INNER + col) = a2;
      *(float4*)(dst + (size_t)(m + 3) * INNER + col) = a3;
    } else {
      int tid = tile - 128;
      int vt = tid & 3, dt = (tid >> 2) % 12, b = tid / 48;
      int v0 = vt * 64, d0 = dt * 64;
      int j = t & 63, i0 = t >> 6;
#pragma unroll
      for (int p = 0; p < 16; p++) {
        int i = p * 4 + i0;
        SB[i * 65 + j] = s_ln[(size_t)(b * VV + v0 + i) * DD + d0 + j];
      }
      __syncthreads();
#pragma unroll
      for (int p = 0; p < 16; p++) {
        int i = p * 4 + i0;
        sT[((size_t)b * DD + d0 + i) * VV + v0 + j] = SB[j * 65 + i];
      }
    }
    __syncthreads();
  }
  target += GRID; gbar(bar, target);

  // ================= Phase 3: qmk (384) | qbk (256) =================
  for (int tile = blockIdx.x; tile < 640; tile += GRID) {
    if (tile < 384) {
      int h = tile & 7, dc = (tile >> 3) % 3, mb = tile / 24;
      int m0 = mb * 16;
#pragma unroll
      for (int p = 0; p < 4; p++) {
        int idx = p * 256 + t, r = idx >> 6, c = idx & 63;
        int i = h * HD + c;
        size_t off = (size_t)(m0 + r) * INNER + i;
        SB[idx] = qp[off] + qp[131072 + off] + qp[262144 + off] +
                  qp[393216 + off] + bq[i];
      }
      __syncthreads();
      int kl = t & 63, wid = t >> 6;
      int col = dc * 256 + 4 * kl;
      const float* A0 = SB + (wid * 4) * HD;
      float4 a0 = {0,0,0,0}, a1 = {0,0,0,0}, a2 = {0,0,0,0}, a3 = {0,0,0,0};
      gcore<64, DD>(A0, HD, WkT + (size_t)(h * HD) * DD + col, a0, a1, a2, a3);
#pragma unroll
      for (int j = 0; j < 4; j++) {
        float4 a = (j == 0) ? a0 : (j == 1) ? a1 : (j == 2) ? a2 : a3;
        int m = m0 + wid * 4 + j;
        const float* mkp = cp + (size_t)m * 2816 + 768 + col;
        float4 o = {a.x * (mkp[0] + 1.0f), a.y * (mkp[1] + 1.0f),
                    a.z * (mkp[2] + 1.0f), a.w * (mkp[3] + 1.0f)};
        *(float4*)(qm + ((size_t)m * NH + h) * DD + col) = o;
      }
    } else {
      int m = tile - 384;
      size_t off = (size_t)m * INNER;
      SB[t] = (qp[off + t] + qp[131072 + off + t] + qp[262144 + off + t] +
               qp[393216 + off + t] + bq[t]) * bk[t];
      int t2 = t + 256;
      SB[t2] = (qp[off + t2] + qp[131072 + off + t2] + qp[262144 + off + t2] +
                qp[393216 + off + t2] + bq[t2]) * bk[t2];
      __syncthreads();
      if (t < 8) {
        float a = 0.f;
        for (int c = 0; c < HD; c++) a += SB[t * HD + c];
        qbk[m * NH + t] = a;
      }
    }
    __syncthreads();
  }
  target += GRID; gbar(bar, target);

  // ================= Phase 4: scores partial (512) =================
  for (int tile = blockIdx.x; tile < 512; tile += GRID) {
    int ks = tile & 3, b = (tile >> 2) & 3, mb = tile >> 4;
    int gi0 = b * 512 + mb * 16, k0 = ks * 192;
#pragma unroll
    for (int p = 0; p < 12; p++) {
      int idx = p * 256 + t, r = idx / 192, k = idx % 192;
      SB[idx] = qm[(size_t)(gi0 + r) * DD + k0 + k];
    }
    __syncthreads();
    int kl = t & 63, wid = t >> 6;
    int col = 4 * kl;
    const float* A0 = SB + (wid * 4) * 192;
    float4 a0 = {0,0,0,0}, a1 = {0,0,0,0}, a2 = {0,0,0,0}, a3 = {0,0,0,0};
    gcore<192, VV>(A0, 192, sT + ((size_t)b * DD + k0) * VV + col, a0, a1, a2, a3);
    int gi = gi0 + wid * 4;
    float* dst = scp + (size_t)ks * (2048 * VV);
    *(float4*)(dst + (size_t)gi * VV + col) = a0;
    *(float4*)(dst + (size_t)(gi + 1) * VV + col) = a1;
    *(float4*)(dst + (size_t)(gi + 2) * VV + col) = a2;
    *(float4*)(dst + (size_t)(gi + 3) * VV + col) = a3;
    __syncthreads();
  }
  target += GRID; gbar(bar, target);

  // ================= Phase 5: softmax + ws GEMM (384) =================
  for (int tile = blockIdx.x; tile < 384; tile += GRID) {
    int dc = tile % 3, up = (tile / 3) % 32, b = tile / 96;
    int gi0 = b * 512 + up * 16;
#pragma unroll
    for (int p = 0; p < 16; p++) {
      int idx = p * 256 + t, r = idx >> 8, c = idx & 255;
      size_t o = (size_t)(gi0 + r) * VV + c;
      float v = scp[o] + scp[524288 + o] + scp[1048576 + o] + scp[1572864 + o];
      int m = b * 64 + up * 2 + (r >> 3), h = r & 7;
      SB[idx] = (v + qbk[m * NH + h]) * 0.125f;
    }
    __syncthreads();
    int wid = t >> 6, lane = t & 63;
#pragma unroll
    for (int j = 0; j < 4; j++) {
      int r = wid * 4 + j;
      float x0 = SB[r * 256 + lane],       x1 = SB[r * 256 + lane + 64];
      float x2 = SB[r * 256 + lane + 128], x3 = SB[r * 256 + lane + 192];
      float mx = fmaxf(fmaxf(x0, x1), fmaxf(x2, x3));
      for (int o = 1; o < 64; o <<= 1) mx = fmaxf(mx, __shfl_xor(mx, o, 64));
      float e0 = __expf(x0 - mx), e1 = __expf(x1 - mx);
      float e2 = __expf(x2 - mx), e3 = __expf(x3 - mx);
      float sm = e0 + e1 + e2 + e3;
      for (int o = 1; o < 64; o <<= 1) sm += __shfl_xor(sm, o, 64);
      float rinv = 1.0f / sm;
      SB[r * 256 + lane] = e0 * rinv;       SB[r * 256 + lane + 64] = e1 * rinv;
      SB[r * 256 + lane + 128] = e2 * rinv; SB[r * 256 + lane + 192] = e3 * rinv;
    }
    __syncthreads();
    int kl = t & 63;
    int col = dc * 256 + 4 * kl;
    const float* A0 = SB + (wid * 4) * 256;
    float4 a0 = {0,0,0,0}, a1 = {0,0,0,0}, a2 = {0,0,0,0}, a3 = {0,0,0,0};
    gcore<VV, DD>(A0, 256, s_ln + (size_t)(b * VV) * DD + col, a0, a1, a2, a3);
#pragma unroll
    for (int j = 0; j < 4; j++) {
      float4 a = (j == 0) ? a0 : (j == 1) ? a1 : (j == 2) ? a2 : a3;
      int r = wid * 4 + j;
      int ul = r >> 3, h = r & 7, m = b * 64 + up * 2 + ul;
      const float* mvp = cp + (size_t)m * 2816 + 1536 + col;
      float4 o = {a.x * (mvp[0] + 1.0f), a.y * (mvp[1] + 1.0f),
                  a.z * (mvp[2] + 1.0f), a.w * (mvp[3] + 1.0f)};
      *(float4*)(wsm + ((size_t)h * 256 + m) * DD + col) = o;
    }
    __syncthreads();
  }
  target += GRID; gbar(bar, target);

  // ================= Phase 6: msg partial (256) =================
  // LDS layout: head-group e at base e*1540 (16 rows x stride 96, +4 pad
  // per group -> groups 4 banks apart, no b128 bank conflicts).
  for (int tile = blockIdx.x; tile < 256; tile += GRID) {
    int hp = tile & 1, ks = (tile >> 1) & 7, mb = tile >> 4;
    int h0 = hp * 4, m0 = mb * 16, k0 = ks * 96;
#pragma unroll
    for (int p = 0; p < 24; p++) {
      int idx = p * 256 + t;
      int e = idx / 1536, rem = idx % 1536, r = rem / 96, k = rem % 96;
      SB[e * 1540 + r * 96 + k] =
          wsm[((size_t)(h0 + e) * 256 + m0 + r) * DD + k0 + k];
    }
    __syncthreads();
    int kl = t & 63, wid = t >> 6;
    int hs = kl >> 4, c4 = 4 * (kl & 15);
    int colg = h0 * HD + hs * HD + c4;
    const float* A0 = SB + hs * 1540 + (wid * 4) * 96;
    float4 a0 = {0,0,0,0}, a1 = {0,0,0,0}, a2 = {0,0,0,0}, a3 = {0,0,0,0};
    gcore<96, INNER>(A0, 96, Wv + (size_t)k0 * INNER + colg, a0, a1, a2, a3);
    float* dst = mmp + (size_t)ks * (256 * INNER);
    int m = m0 + wid * 4;
    *(float4*)(dst + (size_t)m * INNER + colg) = a0;
    *(float4*)(dst + (size_t)(m + 1) * INNER + colg) = a1;
    *(float4*)(dst + (size_t)(m + 2) * INNER + colg) = a2;
    *(float4*)(dst + (size_t)(m + 3) * INNER + colg) = a3;
    __syncthreads();
  }
  target += GRID; gbar(bar, target);

  // ================= Phase 7: out partial (384) =================
  for (int tile = blockIdx.x; tile < 384; tile += GRID) {
    int ks = tile & 7, dc = (tile >> 3) % 3, mb = tile / 24;
    int m0 = mb * 16, k0 = ks * 64;
#pragma unroll
    for (int p = 0; p < 4; p++) {
      int idx = p * 256 + t, r = idx >> 6, k = idx & 63;
      int i = k0 + k;
      size_t off = (size_t)(m0 + r) * INNER + i;
      float v = mmp[off] + mmp[131072 + off] + mmp[262144 + off] +
                mmp[393216 + off] + mmp[524288 + off] + mmp[655360 + off] +
                mmp[786432 + off] + mmp[917504 + off];
      float mev = cp[(size_t)(m0 + r) * 2816 + 2304 + i] + 1.0f;
      SB[idx] = (v + bvv[i]) * mev;
    }
    __syncthreads();
    int kl = t & 63, wid = t >> 6;
    int col = dc * 256 + 4 * kl;
    const float* A0 = SB + (wid * 4) * 64;
    float4 a0 = {0,0,0,0}, a1 = {0,0,0,0}, a2 = {0,0,0,0}, a3 = {0,0,0,0};
    gcore<64, DD>(A0, 64, We + (size_t)k0 * DD + col, a0, a1, a2, a3);
    float* dst = op + (size_t)ks * (256 * DD);
    int m = m0 + wid * 4;
    *(float4*)(dst + (size_t)m * DD + col) = a0;
    *(float4*)(dst + (size_t)(m + 1) * DD + col) = a1;
    *(float4*)(dst + (size_t)(m + 2) * DD + col) = a2;
    *(float4*)(dst + (size_t)(m + 3) * DD + col) = a3;
    __syncthreads();
  }
  target += GRID; gbar(bar, target);

  // ================= Phase 8: epilogue (256) =================
  for (int tile = blockIdx.x; tile < 256; tile += GRID) {
    int m = tile;
#pragma unroll
    for (int j = 0; j < 3; j++) {
      int d = t + j * 256;
      size_t off = (size_t)m * DD + d;
      float v = op[off] + op[196608 + off] + op[393216 + off] +
                op[589824 + off] + op[786432 + off] + op[983040 + off] +
                op[1179648 + off] + op[1376256 + off];
      outp[off] = rs[off] + (v + be[d]) * gamma[d];
    }
  }
}

extern "C" void kernel_launch(void* const* d_in, const int* in_sizes, int n_in,
                              void* d_out, int out_size, void* d_ws, size_t ws_size,
                              hipStream_t stream) {
  const float* rs     = (const float*)d_in[0];
  const float* codes  = (const float*)d_in[1];
  const float* ss     = (const float*)d_in[2];
  const float* ln_r_g = (const float*)d_in[3];
  const float* ln_r_b = (const float*)d_in[4];
  const float* ln_s_g = (const float*)d_in[5];
  const float* ln_s_b = (const float*)d_in[6];
  const float* Wq  = (const float*)d_in[7];
  const float* bq  = (const float*)d_in[8];
  const float* Wmq = (const float*)d_in[9];
  const float* Wk  = (const float*)d_in[10];
  const float* bk  = (const float*)d_in[11];
  const float* Wmk = (const float*)d_in[12];
  const float* Wv  = (const float*)d_in[13];
  const float* bv  = (const float*)d_in[14];
  const float* Wmv = (const float*)d_in[15];
  const float* We  = (const float*)d_in[16];
  const float* be  = (const float*)d_in[17];
  const float* Wme = (const float*)d_in[18];
  const float* gamma = (const float*)d_in[19];

  float* w = (float*)d_ws;
  unsigned* bar = (unsigned*)(w + 7079936);   // past 28.3 MB working set

  hipMemsetAsync(bar, 0, 64, stream);
  k_all<<<dim3(GRID), 256, 0, stream>>>(
      rs, codes, ss, ln_r_g, ln_r_b, ln_s_g, ln_s_b, Wq, bq, Wmq, Wk, bk,
      Wmk, Wv, bv, Wmv, We, be, Wme, gamma, w, (float*)d_out, bar);
}

// Round 10
// 213.350 us; speedup vs baseline: 2.6270x; 2.6270x over previous
//
#include <hip/hip_runtime.h>

// ReadInAttention — 7-launch f32 pipeline (revert of persistent experiment).
// gcore: 4 rows x float4/thread, dual 8-deep global prefetch, b128 LDS
// A-reads (wave-broadcast, conflict-free). Epilogue folded into s7 via
// atomicAdd(out, partial*gamma); out pre-initialized to rs + be*gamma in s1.

#define DD 768
#define CDIM 384
#define NH 8
#define HD 64
#define INNER 512
#define VV 256

__device__ __forceinline__ void fma4(float4& a, float s, const float4& b) {
  a.x += s * b.x; a.y += s * b.y; a.z += s * b.z; a.w += s * b.w;
}

// A0: LDS (16B-aligned, lda multiple of 4). B: global, row stride NS.
template <int K, int NS>
__device__ __forceinline__ void gcore(const float* __restrict__ A0, int lda,
                                      const float* __restrict__ Bp,
                                      float4& a0, float4& a1, float4& a2,
                                      float4& a3) {
  float4 b0[8], b1[8];
#pragma unroll
  for (int i = 0; i < 8; i++) b0[i] = *(const float4*)(Bp + (size_t)i * NS);
  const float* Bq = Bp + (size_t)8 * NS;
#pragma unroll 1
  for (int kk = 0; kk < K; kk += 16) {
#pragma unroll
    for (int i = 0; i < 8; i++) b1[i] = *(const float4*)(Bq + (size_t)i * NS);
    Bq += (size_t)8 * NS;
#pragma unroll
    for (int c = 0; c < 2; c++) {
      int kb = kk + c * 4;
      float4 f0 = *(const float4*)(A0 + kb);
      float4 f1 = *(const float4*)(A0 + lda + kb);
      float4 f2 = *(const float4*)(A0 + 2 * lda + kb);
      float4 f3 = *(const float4*)(A0 + 3 * lda + kb);
      float4 bv;
      bv = b0[c*4+0]; fma4(a0,f0.x,bv); fma4(a1,f1.x,bv); fma4(a2,f2.x,bv); fma4(a3,f3.x,bv);
      bv = b0[c*4+1]; fma4(a0,f0.y,bv); fma4(a1,f1.y,bv); fma4(a2,f2.y,bv); fma4(a3,f3.y,bv);
      bv = b0[c*4+2]; fma4(a0,f0.z,bv); fma4(a1,f1.z,bv); fma4(a2,f2.z,bv); fma4(a3,f3.z,bv);
      bv = b0[c*4+3]; fma4(a0,f0.w,bv); fma4(a1,f1.w,bv); fma4(a2,f2.w,bv); fma4(a3,f3.w,bv);
    }
    if (kk + 16 < K) {
#pragma unroll
      for (int i = 0; i < 8; i++) b0[i] = *(const float4*)(Bq + (size_t)i * NS);
      Bq += (size_t)8 * NS;
    }
#pragma unroll
    for (int c = 0; c < 2; c++) {
      int kb = kk + 8 + c * 4;
      float4 f0 = *(const float4*)(A0 + kb);
      float4 f1 = *(const float4*)(A0 + lda + kb);
      float4 f2 = *(const float4*)(A0 + 2 * lda + kb);
      float4 f3 = *(const float4*)(A0 + 3 * lda + kb);
      float4 bv;
      bv = b1[c*4+0]; fma4(a0,f0.x,bv); fma4(a1,f1.x,bv); fma4(a2,f2.x,bv); fma4(a3,f3.x,bv);
      bv = b1[c*4+1]; fma4(a0,f0.y,bv); fma4(a1,f1.y,bv); fma4(a2,f2.y,bv); fma4(a3,f3.y,bv);
      bv = b1[c*4+2]; fma4(a0,f0.z,bv); fma4(a1,f1.z,bv); fma4(a2,f2.z,bv); fma4(a3,f3.z,bv);
      bv = b1[c*4+3]; fma4(a0,f0.w,bv); fma4(a1,f1.w,bv); fma4(a2,f2.w,bv); fma4(a3,f3.w,bv);
    }
  }
}

// ===== Stage 1: code GEMM [0,176) | WkT [176,272) | LN+out-preinit ========
__global__ __launch_bounds__(256, 2) void k_s1(
    const float* __restrict__ ss, const float* __restrict__ rs,
    const float* __restrict__ g_s, const float* __restrict__ b_s,
    const float* __restrict__ g_r, const float* __restrict__ b_r,
    const float* __restrict__ codes, const float* __restrict__ Wmq,
    const float* __restrict__ Wmk, const float* __restrict__ Wmv,
    const float* __restrict__ Wme, const float* __restrict__ Wk,
    const float* __restrict__ be, const float* __restrict__ gamma,
    float* __restrict__ s_ln, float* __restrict__ r_ln,
    float* __restrict__ cp, float* __restrict__ WkT,
    float* __restrict__ outp) {
  __shared__ __align__(16) float SB[6400];
  int bid = blockIdx.x, t = threadIdx.x;
  if (bid < 176) {
    int nc = bid % 11, mb = bid / 11;
    int base = nc * 256;
    const float* W; int N, colW;
    if (base < 768)       { W = Wmq; N = DD;    colW = base; }
    else if (base < 1536) { W = Wmk; N = DD;    colW = base - 768; }
    else if (base < 2304) { W = Wmv; N = DD;    colW = base - 1536; }
    else                  { W = Wme; N = INNER; colW = base - 2304; }
    int m0 = mb * 16;
#pragma unroll
    for (int p = 0; p < 24; p++) {
      int idx = p * 256 + t, r = idx / 384, k = idx % 384;
      SB[idx] = codes[(size_t)(m0 + r) * CDIM + k];
    }
    __syncthreads();
    int kl = t & 63, wid = t >> 6;
    const float* A0 = SB + (wid * 4) * 384;
    float4 a0 = {0,0,0,0}, a1 = {0,0,0,0}, a2 = {0,0,0,0}, a3 = {0,0,0,0};
    if (N == DD)
      gcore<384, DD>(A0, 384, W + colW + 4 * kl, a0, a1, a2, a3);
    else
      gcore<384, INNER>(A0, 384, W + colW + 4 * kl, a0, a1, a2, a3);
    int m = m0 + wid * 4, gcol = base + 4 * kl;
    *(float4*)(cp + (size_t)m * 2816 + gcol) = a0;
    *(float4*)(cp + (size_t)(m + 1) * 2816 + gcol) = a1;
    *(float4*)(cp + (size_t)(m + 2) * 2816 + gcol) = a2;
    *(float4*)(cp + (size_t)(m + 3) * 2816 + gcol) = a3;
  } else if (bid < 272) {
    int tid = bid - 176;
    int d0 = (tid >> 3) * 64, c0 = (tid & 7) * 64;
    int j = t & 63, i0 = t >> 6;
#pragma unroll
    for (int p = 0; p < 16; p++) {
      int i = p * 4 + i0;
      SB[i * 65 + j] = Wk[(size_t)(d0 + i) * INNER + c0 + j];
    }
    __syncthreads();
#pragma unroll
    for (int p = 0; p < 16; p++) {
      int i = p * 4 + i0;
      WkT[(size_t)(c0 + i) * DD + d0 + j] = SB[j * 65 + i];
    }
  } else {
    int rr = bid - 272;
    const float *x, *g, *bb; float* y; int r; bool isR;
    if (rr < 1024) { x = ss; g = g_s; bb = b_s; y = s_ln; r = rr; isR = false; }
    else           { x = rs; g = g_r; bb = b_r; y = r_ln; r = rr - 1024; isR = true; }
    const float* xr = x + (size_t)r * DD;
    float v0 = xr[t], v1 = xr[t + 256], v2 = xr[t + 512];
    float s = v0 + v1 + v2, sq = v0 * v0 + v1 * v1 + v2 * v2;
    for (int o = 32; o > 0; o >>= 1) {
      s += __shfl_down(s, o, 64); sq += __shfl_down(sq, o, 64);
    }
    int wid = t >> 6, lane = t & 63;
    if (lane == 0) { SB[wid] = s; SB[wid + 4] = sq; }
    __syncthreads();
    float sum = SB[0] + SB[1] + SB[2] + SB[3];
    float ssq = SB[4] + SB[5] + SB[6] + SB[7];
    float mu = sum * (1.0f / 768.0f);
    float var = ssq * (1.0f / 768.0f) - mu * mu;
    float rstd = rsqrtf(var + 1e-5f);
    float* yr = y + (size_t)r * DD;
    yr[t]       = (v0 - mu) * rstd * g[t]       + bb[t];
    yr[t + 256] = (v1 - mu) * rstd * g[t + 256] + bb[t + 256];
    yr[t + 512] = (v2 - mu) * rstd * g[t + 512] + bb[t + 512];
    if (isR) {  // pre-init out = rs + be*gamma (v0..v2 are the rs row)
      float* orow = outp + (size_t)r * DD;
      orow[t]       = v0 + be[t]       * gamma[t];
      orow[t + 256] = v1 + be[t + 256] * gamma[t + 256];
      orow[t + 512] = v2 + be[t + 512] * gamma[t + 512];
    }
  }
}

// ===== Stage 2: q partial [0,128) (Kc=192, ks=4) | sT [128,320) ============
__global__ __launch_bounds__(256, 2) void k_s2(
    const float* __restrict__ s_ln, const float* __restrict__ r_ln,
    const float* __restrict__ cp, const float* __restrict__ Wq,
    float* __restrict__ sT, float* __restrict__ qp) {
  __shared__ __align__(16) float SB[4160];
  int bid = blockIdx.x, t = threadIdx.x;
  if (bid < 128) {
    int ks = bid & 3, t2 = bid >> 2, nc = t2 & 1, mb = t2 >> 1;
    int m0 = mb * 16, col0 = nc * 256, k0 = ks * 192;
#pragma unroll
    for (int p = 0; p < 12; p++) {
      int idx = p * 256 + t, r = idx / 192, k = idx % 192;
      int d = k0 + k;
      float mqv = cp[(size_t)(m0 + r) * 2816 + d] + 1.0f;
      SB[idx] = r_ln[(size_t)(m0 + r) * DD + d] * mqv;
    }
    __syncthreads();
    int kl = t & 63, wid = t >> 6;
    int col = col0 + 4 * kl;
    const float* A0 = SB + (wid * 4) * 192;
    float4 a0 = {0,0,0,0}, a1 = {0,0,0,0}, a2 = {0,0,0,0}, a3 = {0,0,0,0};
    gcore<192, INNER>(A0, 192, Wq + (size_t)k0 * INNER + col, a0, a1, a2, a3);
    int m = m0 + wid * 4;
    float* dst = qp + (size_t)ks * (256 * INNER);
    *(float4*)(dst + (size_t)m * INNER + col) = a0;
    *(float4*)(dst + (size_t)(m + 1) * INNER + col) = a1;
    *(float4*)(dst + (size_t)(m + 2) * INNER + col) = a2;
    *(float4*)(dst + (size_t)(m + 3) * INNER + col) = a3;
  } else {
    int tid = bid - 128;
    int vt = tid & 3, dt = (tid >> 2) % 12, b = tid / 48;
    int v0 = vt * 64, d0 = dt * 64;
    int j = t & 63, i0 = t >> 6;
#pragma unroll
    for (int p = 0; p < 16; p++) {
      int i = p * 4 + i0;
      SB[i * 65 + j] = s_ln[(size_t)(b * VV + v0 + i) * DD + d0 + j];
    }
    __syncthreads();
#pragma unroll
    for (int p = 0; p < 16; p++) {
      int i = p * 4 + i0;
      sT[((size_t)b * DD + d0 + i) * VV + v0 + j] = SB[j * 65 + i];
    }
  }
}

// ===== Stage 3: qmk [0,384) (K=64) | qbk [384,640) =========================
__global__ __launch_bounds__(256, 2) void k_s3(
    const float* __restrict__ qp, const float* __restrict__ bq,
    const float* __restrict__ WkT, const float* __restrict__ cp,
    const float* __restrict__ bk, float* __restrict__ qm,
    float* __restrict__ qbk) {
  __shared__ __align__(16) float SB[1024];
  int bid = blockIdx.x, t = threadIdx.x;
  if (bid < 384) {
    int h = bid & 7, dc = (bid >> 3) % 3, mb = bid / 24;
    int m0 = mb * 16;
#pragma unroll
    for (int p = 0; p < 4; p++) {
      int idx = p * 256 + t, r = idx >> 6, c = idx & 63;
      int i = h * HD + c;
      size_t off = (size_t)(m0 + r) * INNER + i;
      SB[idx] = qp[off] + qp[131072 + off] + qp[262144 + off] +
                qp[393216 + off] + bq[i];
    }
    __syncthreads();
    int kl = t & 63, wid = t >> 6;
    int col = dc * 256 + 4 * kl;
    const float* A0 = SB + (wid * 4) * HD;
    float4 a0 = {0,0,0,0}, a1 = {0,0,0,0}, a2 = {0,0,0,0}, a3 = {0,0,0,0};
    gcore<64, DD>(A0, HD, WkT + (size_t)(h * HD) * DD + col, a0, a1, a2, a3);
#pragma unroll
    for (int j = 0; j < 4; j++) {
      float4 a = (j == 0) ? a0 : (j == 1) ? a1 : (j == 2) ? a2 : a3;
      int m = m0 + wid * 4 + j;
      const float* mkp = cp + (size_t)m * 2816 + 768 + col;
      float4 o = {a.x * (mkp[0] + 1.0f), a.y * (mkp[1] + 1.0f),
                  a.z * (mkp[2] + 1.0f), a.w * (mkp[3] + 1.0f)};
      *(float4*)(qm + ((size_t)m * NH + h) * DD + col) = o;
    }
  } else {
    int m = bid - 384;
    size_t off = (size_t)m * INNER;
    SB[t] = (qp[off + t] + qp[131072 + off + t] + qp[262144 + off + t] +
             qp[393216 + off + t] + bq[t]) * bk[t];
    int t2 = t + 256;
    SB[t2] = (qp[off + t2] + qp[131072 + off + t2] + qp[262144 + off + t2] +
              qp[393216 + off + t2] + bq[t2]) * bk[t2];
    __syncthreads();
    if (t < 8) {
      float a = 0.f;
      for (int c = 0; c < HD; c++) a += SB[t * HD + c];
      qbk[m * NH + t] = a;
    }
  }
}

// ===== Stage 4: scores partial (512 blocks, Kc=192, ks=4) ==================
__global__ __launch_bounds__(256, 2) void k_s4(
    const float* __restrict__ qm, const float* __restrict__ sT,
    float* __restrict__ scp) {
  __shared__ __align__(16) float SB[3072];
  int bid = blockIdx.x, t = threadIdx.x;
  int ks = bid & 3, b = (bid >> 2) & 3, mb = bid >> 4;
  int gi0 = b * 512 + mb * 16, k0 = ks * 192;
#pragma unroll
  for (int p = 0; p < 12; p++) {
    int idx = p * 256 + t, r = idx / 192, k = idx % 192;
    SB[idx] = qm[(size_t)(gi0 + r) * DD + k0 + k];
  }
  __syncthreads();
  int kl = t & 63, wid = t >> 6;
  int col = 4 * kl;
  const float* A0 = SB + (wid * 4) * 192;
  float4 a0 = {0,0,0,0}, a1 = {0,0,0,0}, a2 = {0,0,0,0}, a3 = {0,0,0,0};
  gcore<192, VV>(A0, 192, sT + ((size_t)b * DD + k0) * VV + col, a0, a1, a2, a3);
  int gi = gi0 + wid * 4;
  float* dst = scp + (size_t)ks * (2048 * VV);
  *(float4*)(dst + (size_t)gi * VV + col) = a0;
  *(float4*)(dst + (size_t)(gi + 1) * VV + col) = a1;
  *(float4*)(dst + (size_t)(gi + 2) * VV + col) = a2;
  *(float4*)(dst + (size_t)(gi + 3) * VV + col) = a3;
}

// ===== Stage 5: softmax + ws GEMM (384 blocks, K=256) ======================
__global__ __launch_bounds__(256, 2) void k_s5(
    const float* __restrict__ scp, const float* __restrict__ qbk,
    const float* __restrict__ s_ln, const float* __restrict__ cp,
    float* __restrict__ wsm) {
  __shared__ __align__(16) float SB[4096];
  int bid = blockIdx.x, t = threadIdx.x;
  int dc = bid % 3, up = (bid / 3) % 32, b = bid / 96;
  int gi0 = b * 512 + up * 16;
#pragma unroll
  for (int p = 0; p < 16; p++) {
    int idx = p * 256 + t, r = idx >> 8, c = idx & 255;
    size_t o = (size_t)(gi0 + r) * VV + c;
    float v = scp[o] + scp[524288 + o] + scp[1048576 + o] + scp[1572864 + o];
    int m = b * 64 + up * 2 + (r >> 3), h = r & 7;
    SB[idx] = (v + qbk[m * NH + h]) * 0.125f;
  }
  __syncthreads();
  int wid = t >> 6, lane = t & 63;
#pragma unroll
  for (int j = 0; j < 4; j++) {
    int r = wid * 4 + j;
    float x0 = SB[r * 256 + lane],       x1 = SB[r * 256 + lane + 64];
    float x2 = SB[r * 256 + lane + 128], x3 = SB[r * 256 + lane + 192];
    float mx = fmaxf(fmaxf(x0, x1), fmaxf(x2, x3));
    for (int o = 1; o < 64; o <<= 1) mx = fmaxf(mx, __shfl_xor(mx, o, 64));
    float e0 = __expf(x0 - mx), e1 = __expf(x1 - mx);
    float e2 = __expf(x2 - mx), e3 = __expf(x3 - mx);
    float sm = e0 + e1 + e2 + e3;
    for (int o = 1; o < 64; o <<= 1) sm += __shfl_xor(sm, o, 64);
    float rinv = 1.0f / sm;
    SB[r * 256 + lane] = e0 * rinv;       SB[r * 256 + lane + 64] = e1 * rinv;
    SB[r * 256 + lane + 128] = e2 * rinv; SB[r * 256 + lane + 192] = e3 * rinv;
  }
  __syncthreads();
  int kl = t & 63;
  int col = dc * 256 + 4 * kl;
  const float* A0 = SB + (wid * 4) * 256;
  float4 a0 = {0,0,0,0}, a1 = {0,0,0,0}, a2 = {0,0,0,0}, a3 = {0,0,0,0};
  gcore<VV, DD>(A0, 256, s_ln + (size_t)(b * VV) * DD + col, a0, a1, a2, a3);
#pragma unroll
  for (int j = 0; j < 4; j++) {
    float4 a = (j == 0) ? a0 : (j == 1) ? a1 : (j == 2) ? a2 : a3;
    int r = wid * 4 + j;
    int ul = r >> 3, h = r & 7, m = b * 64 + up * 2 + ul;
    const float* mvp = cp + (size_t)m * 2816 + 1536 + col;
    float4 o = {a.x * (mvp[0] + 1.0f), a.y * (mvp[1] + 1.0f),
                a.z * (mvp[2] + 1.0f), a.w * (mvp[3] + 1.0f)};
    *(float4*)(wsm + ((size_t)h * 256 + m) * DD + col) = o;
  }
}

// ===== Stage 6: msg partial (256 blocks, Kc=96, ks=8) ======================
// LDS: head-group e at base e*1540 -> groups 4 banks apart, no conflicts.
__global__ __launch_bounds__(256, 2) void k_s6(
    const float* __restrict__ wsm, const float* __restrict__ Wv,
    float* __restrict__ mmp) {
  __shared__ __align__(16) float SB[6400];
  int bid = blockIdx.x, t = threadIdx.x;
  int hp = bid & 1, ks = (bid >> 1) & 7, mb = bid >> 4;
  int h0 = hp * 4, m0 = mb * 16, k0 = ks * 96;
#pragma unroll
  for (int p = 0; p < 24; p++) {
    int idx = p * 256 + t;
    int e = idx / 1536, rem = idx % 1536, r = rem / 96, k = rem % 96;
    SB[e * 1540 + r * 96 + k] =
        wsm[((size_t)(h0 + e) * 256 + m0 + r) * DD + k0 + k];
  }
  __syncthreads();
  int kl = t & 63, wid = t >> 6;
  int hs = kl >> 4, c4 = 4 * (kl & 15);
  int colg = h0 * HD + hs * HD + c4;
  const float* A0 = SB + hs * 1540 + (wid * 4) * 96;
  float4 a0 = {0,0,0,0}, a1 = {0,0,0,0}, a2 = {0,0,0,0}, a3 = {0,0,0,0};
  gcore<96, INNER>(A0, 96, Wv + (size_t)k0 * INNER + colg, a0, a1, a2, a3);
  float* dst = mmp + (size_t)ks * (256 * INNER);
  int m = m0 + wid * 4;
  *(float4*)(dst + (size_t)m * INNER + colg) = a0;
  *(float4*)(dst + (size_t)(m + 1) * INNER + colg) = a1;
  *(float4*)(dst + (size_t)(m + 2) * INNER + colg) = a2;
  *(float4*)(dst + (size_t)(m + 3) * INNER + colg) = a3;
}

// ===== Stage 7: out partial + fused epilogue (384 blocks, Kc=64, ks=8) =====
__global__ __launch_bounds__(256, 2) void k_s7(
    const float* __restrict__ mmp, const float* __restrict__ bvv,
    const float* __restrict__ cp, const float* __restrict__ We,
    const float* __restrict__ gamma, float* __restrict__ outp) {
  __shared__ __align__(16) float SB[1024];
  int bid = blockIdx.x, t = threadIdx.x;
  int ks = bid & 7, dc = (bid >> 3) % 3, mb = bid / 24;
  int m0 = mb * 16, k0 = ks * 64;
#pragma unroll
  for (int p = 0; p < 4; p++) {
    int idx = p * 256 + t, r = idx >> 6, k = idx & 63;
    int i = k0 + k;
    size_t off = (size_t)(m0 + r) * INNER + i;
    float v = mmp[off] + mmp[131072 + off] + mmp[262144 + off] +
              mmp[393216 + off] + mmp[524288 + off] + mmp[655360 + off] +
              mmp[786432 + off] + mmp[917504 + off];
    float mev = cp[(size_t)(m0 + r) * 2816 + 2304 + i] + 1.0f;
    SB[idx] = (v + bvv[i]) * mev;
  }
  __syncthreads();
  int kl = t & 63, wid = t >> 6;
  int col = dc * 256 + 4 * kl;
  const float* A0 = SB + (wid * 4) * 64;
  float4 a0 = {0,0,0,0}, a1 = {0,0,0,0}, a2 = {0,0,0,0}, a3 = {0,0,0,0};
  gcore<64, DD>(A0, 64, We + (size_t)k0 * DD + col, a0, a1, a2, a3);
  float4 g4 = *(const float4*)(gamma + col);
  int m = m0 + wid * 4;
#pragma unroll
  for (int j = 0; j < 4; j++) {
    float4 a = (j == 0) ? a0 : (j == 1) ? a1 : (j == 2) ? a2 : a3;
    float* orow = outp + (size_t)(m + j) * DD + col;
    unsafeAtomicAdd(orow + 0, a.x * g4.x);
    unsafeAtomicAdd(orow + 1, a.y * g4.y);
    unsafeAtomicAdd(orow + 2, a.z * g4.z);
    unsafeAtomicAdd(orow + 3, a.w * g4.w);
  }
}

extern "C" void kernel_launch(void* const* d_in, const int* in_sizes, int n_in,
                              void* d_out, int out_size, void* d_ws, size_t ws_size,
                              hipStream_t stream) {
  const float* rs     = (const float*)d_in[0];
  const float* codes  = (const float*)d_in[1];
  const float* ss     = (const float*)d_in[2];
  const float* ln_r_g = (const float*)d_in[3];
  const float* ln_r_b = (const float*)d_in[4];
  const float* ln_s_g = (const float*)d_in[5];
  const float* ln_s_b = (const float*)d_in[6];
  const float* Wq  = (const float*)d_in[7];
  const float* bq  = (const float*)d_in[8];
  const float* Wmq = (const float*)d_in[9];
  const float* Wk  = (const float*)d_in[10];
  const float* bk  = (const float*)d_in[11];
  const float* Wmk = (const float*)d_in[12];
  const float* Wv  = (const float*)d_in[13];
  const float* bv  = (const float*)d_in[14];
  const float* Wmv = (const float*)d_in[15];
  const float* We  = (const float*)d_in[16];
  const float* be  = (const float*)d_in[17];
  const float* Wme = (const float*)d_in[18];
  const float* gamma = (const float*)d_in[19];

  float* w = (float*)d_ws;
  // liveness-aliased layout (float offsets); peak ≈ 28.3 MB
  float* s_ln = w;                  // 786432   (s1 -> s5)
  float* r_ln = w + 786432;         // 196608   (s1 -> s2)
  float* WkT  = w + 983040;         // 393216   (s1 -> s3)
  float* qp   = w + 1376256;        // 524288   (s2 -> s3, 4 partials)
  float* sT   = w + 1900544;        // 786432   (s2 -> s4)
  float* cp   = w + 2686976;        // 720896   (s1 -> s7) [m][2816]
  float* qbk  = w + 3407872;        // 2048     (s3 -> s5)
  float* qm   = w + 3409920;        // 1572864  (s3 -> s4)
  float* scp  = w + 4982784;        // 2097152  (s4 -> s5, 4 partials)
  float* wsm  = qm;                 // alias: qm dead after s4 (s5 -> s6)
  float* mmp  = r_ln;               // alias r_ln+WkT+qp dead (s6 -> s7, 8 partials)

  k_s1<<<dim3(1552), 256, 0, stream>>>(ss, rs, ln_s_g, ln_s_b, ln_r_g, ln_r_b,
                                       codes, Wmq, Wmk, Wmv, Wme, Wk, be, gamma,
                                       s_ln, r_ln, cp, WkT, (float*)d_out);
  k_s2<<<dim3(320), 256, 0, stream>>>(s_ln, r_ln, cp, Wq, sT, qp);
  k_s3<<<dim3(640), 256, 0, stream>>>(qp, bq, WkT, cp, bk, qm, qbk);
  k_s4<<<dim3(512), 256, 0, stream>>>(qm, sT, scp);
  k_s5<<<dim3(384), 256, 0, stream>>>(scp, qbk, s_ln, cp, wsm);
  k_s6<<<dim3(256), 256, 0, stream>>>(wsm, Wv, mmp);
  k_s7<<<dim3(384), 256, 0, stream>>>(mmp, bv, cp, We, gamma, (float*)d_out);
}

// Round 11
// 204.693 us; speedup vs baseline: 2.7381x; 1.0423x over previous
//
#include <hip/hip_runtime.h>

// ReadInAttention — 9-launch pipeline. s0 converts all weights f32->bf16
// (Wk transposed) at high concurrency so weight-B GEMMs stream half the
// bytes from L2/L3. gcore (f32 B) / gcoreb (bf16 B): 4 rows x float4 per
// thread, dual 8-deep prefetch, b128 LDS A-reads. f32 accumulation.

#define DD 768
#define CDIM 384
#define NH 8
#define HD 64
#define INNER 512
#define VV 256

typedef unsigned short u16;

__device__ __forceinline__ void fma4(float4& a, float s, const float4& b) {
  a.x += s * b.x; a.y += s * b.y; a.z += s * b.z; a.w += s * b.w;
}

__device__ __forceinline__ float4 bexp(uint2 u) {
  float4 r;
  r.x = __uint_as_float(u.x << 16);
  r.y = __uint_as_float(u.x & 0xffff0000u);
  r.z = __uint_as_float(u.y << 16);
  r.w = __uint_as_float(u.y & 0xffff0000u);
  return r;
}

__device__ __forceinline__ u16 f2b(float v) {
  return (u16)((__float_as_uint(v) + 0x8000u) >> 16);
}

// f32 B stream
template <int K, int NS>
__device__ __forceinline__ void gcore(const float* __restrict__ A0, int lda,
                                      const float* __restrict__ Bp,
                                      float4& a0, float4& a1, float4& a2,
                                      float4& a3) {
  float4 b0[8], b1[8];
#pragma unroll
  for (int i = 0; i < 8; i++) b0[i] = *(const float4*)(Bp + (size_t)i * NS);
  const float* Bq = Bp + (size_t)8 * NS;
#pragma unroll 1
  for (int kk = 0; kk < K; kk += 16) {
#pragma unroll
    for (int i = 0; i < 8; i++) b1[i] = *(const float4*)(Bq + (size_t)i * NS);
    Bq += (size_t)8 * NS;
#pragma unroll
    for (int c = 0; c < 2; c++) {
      int kb = kk + c * 4;
      float4 f0 = *(const float4*)(A0 + kb);
      float4 f1 = *(const float4*)(A0 + lda + kb);
      float4 f2 = *(const float4*)(A0 + 2 * lda + kb);
      float4 f3 = *(const float4*)(A0 + 3 * lda + kb);
      float4 bv;
      bv = b0[c*4+0]; fma4(a0,f0.x,bv); fma4(a1,f1.x,bv); fma4(a2,f2.x,bv); fma4(a3,f3.x,bv);
      bv = b0[c*4+1]; fma4(a0,f0.y,bv); fma4(a1,f1.y,bv); fma4(a2,f2.y,bv); fma4(a3,f3.y,bv);
      bv = b0[c*4+2]; fma4(a0,f0.z,bv); fma4(a1,f1.z,bv); fma4(a2,f2.z,bv); fma4(a3,f3.z,bv);
      bv = b0[c*4+3]; fma4(a0,f0.w,bv); fma4(a1,f1.w,bv); fma4(a2,f2.w,bv); fma4(a3,f3.w,bv);
    }
    if (kk + 16 < K) {
#pragma unroll
      for (int i = 0; i < 8; i++) b0[i] = *(const float4*)(Bq + (size_t)i * NS);
      Bq += (size_t)8 * NS;
    }
#pragma unroll
    for (int c = 0; c < 2; c++) {
      int kb = kk + 8 + c * 4;
      float4 f0 = *(const float4*)(A0 + kb);
      float4 f1 = *(const float4*)(A0 + lda + kb);
      float4 f2 = *(const float4*)(A0 + 2 * lda + kb);
      float4 f3 = *(const float4*)(A0 + 3 * lda + kb);
      float4 bv;
      bv = b1[c*4+0]; fma4(a0,f0.x,bv); fma4(a1,f1.x,bv); fma4(a2,f2.x,bv); fma4(a3,f3.x,bv);
      bv = b1[c*4+1]; fma4(a0,f0.y,bv); fma4(a1,f1.y,bv); fma4(a2,f2.y,bv); fma4(a3,f3.y,bv);
      bv = b1[c*4+2]; fma4(a0,f0.z,bv); fma4(a1,f1.z,bv); fma4(a2,f2.z,bv); fma4(a3,f3.z,bv);
      bv = b1[c*4+3]; fma4(a0,f0.w,bv); fma4(a1,f1.w,bv); fma4(a2,f2.w,bv); fma4(a3,f3.w,bv);
    }
  }
}

// bf16 B stream (ushort4 loads, expand to f32)
template <int K, int NS>
__device__ __forceinline__ void gcoreb(const float* __restrict__ A0, int lda,
                                       const u16* __restrict__ Bp,
                                       float4& a0, float4& a1, float4& a2,
                                       float4& a3) {
  uint2 b0[8], b1[8];
#pragma unroll
  for (int i = 0; i < 8; i++) b0[i] = *(const uint2*)(Bp + (size_t)i * NS);
  const u16* Bq = Bp + (size_t)8 * NS;
#pragma unroll 1
  for (int kk = 0; kk < K; kk += 16) {
#pragma unroll
    for (int i = 0; i < 8; i++) b1[i] = *(const uint2*)(Bq + (size_t)i * NS);
    Bq += (size_t)8 * NS;
#pragma unroll
    for (int c = 0; c < 2; c++) {
      int kb = kk + c * 4;
      float4 f0 = *(const float4*)(A0 + kb);
      float4 f1 = *(const float4*)(A0 + lda + kb);
      float4 f2 = *(const float4*)(A0 + 2 * lda + kb);
      float4 f3 = *(const float4*)(A0 + 3 * lda + kb);
      float4 bv;
      bv = bexp(b0[c*4+0]); fma4(a0,f0.x,bv); fma4(a1,f1.x,bv); fma4(a2,f2.x,bv); fma4(a3,f3.x,bv);
      bv = bexp(b0[c*4+1]); fma4(a0,f0.y,bv); fma4(a1,f1.y,bv); fma4(a2,f2.y,bv); fma4(a3,f3.y,bv);
      bv = bexp(b0[c*4+2]); fma4(a0,f0.z,bv); fma4(a1,f1.z,bv); fma4(a2,f2.z,bv); fma4(a3,f3.z,bv);
      bv = bexp(b0[c*4+3]); fma4(a0,f0.w,bv); fma4(a1,f1.w,bv); fma4(a2,f2.w,bv); fma4(a3,f3.w,bv);
    }
    if (kk + 16 < K) {
#pragma unroll
      for (int i = 0; i < 8; i++) b0[i] = *(const uint2*)(Bq + (size_t)i * NS);
      Bq += (size_t)8 * NS;
    }
#pragma unroll
    for (int c = 0; c < 2; c++) {
      int kb = kk + 8 + c * 4;
      float4 f0 = *(const float4*)(A0 + kb);
      float4 f1 = *(const float4*)(A0 + lda + kb);
      float4 f2 = *(const float4*)(A0 + 2 * lda + kb);
      float4 f3 = *(const float4*)(A0 + 3 * lda + kb);
      float4 bv;
      bv = bexp(b1[c*4+0]); fma4(a0,f0.x,bv); fma4(a1,f1.x,bv); fma4(a2,f2.x,bv); fma4(a3,f3.x,bv);
      bv = bexp(b1[c*4+1]); fma4(a0,f0.y,bv); fma4(a1,f1.y,bv); fma4(a2,f2.y,bv); fma4(a3,f3.y,bv);
      bv = bexp(b1[c*4+2]); fma4(a0,f0.z,bv); fma4(a1,f1.z,bv); fma4(a2,f2.z,bv); fma4(a3,f3.z,bv);
      bv = bexp(b1[c*4+3]); fma4(a0,f0.w,bv); fma4(a1,f1.w,bv); fma4(a2,f2.w,bv); fma4(a3,f3.w,bv);
    }
  }
}

// bw layout (ushort offsets):
// bWmq 0 | bWmk 294912 | bWmv 589824 | bWme 884736 | bWq 1081344 |
// bWv 1474560 | bWe 1867776 | bWkT 2260992 | end 2654208

// ===== Stage 0: weight convert f32->bf16 (+ Wk transpose). 1280 blocks =====
__global__ __launch_bounds__(256) void k_s0(
    const float* __restrict__ Wmq, const float* __restrict__ Wmk,
    const float* __restrict__ Wmv, const float* __restrict__ Wme,
    const float* __restrict__ Wq, const float* __restrict__ Wk,
    const float* __restrict__ Wv, const float* __restrict__ We,
    u16* __restrict__ bw) {
  __shared__ float TL[64 * 65];
  int bid = blockIdx.x, t = threadIdx.x;
  if (bid < 96) {  // transpose-convert Wk[768][512] -> bWkT[512][768]
    int d0 = (bid >> 3) * 64, c0 = (bid & 7) * 64;
    int j = t & 63, i0 = t >> 6;
#pragma unroll
    for (int p = 0; p < 16; p++) {
      int i = p * 4 + i0;
      TL[i * 65 + j] = Wk[(size_t)(d0 + i) * INNER + c0 + j];
    }
    __syncthreads();
    u16* dst = bw + 2260992;
#pragma unroll
    for (int p = 0; p < 16; p++) {
      int i = p * 4 + i0;
      dst[(size_t)(c0 + i) * DD + d0 + j] = f2b(TL[j * 65 + i]);
    }
  } else {  // plain convert, float4-granular grid-stride
    for (int idx = (bid - 96) * 256 + t; idx < 565248; idx += 1184 * 256) {
      const float* src; u16* dst; int off;
      if (idx < 73728)       { src = Wmq; dst = bw;           off = idx; }
      else if (idx < 147456) { src = Wmk; dst = bw + 294912;  off = idx - 73728; }
      else if (idx < 221184) { src = Wmv; dst = bw + 589824;  off = idx - 147456; }
      else if (idx < 270336) { src = Wme; dst = bw + 884736;  off = idx - 221184; }
      else if (idx < 368640) { src = Wq;  dst = bw + 1081344; off = idx - 270336; }
      else if (idx < 466944) { src = Wv;  dst = bw + 1474560; off = idx - 368640; }
      else                   { src = We;  dst = bw + 1867776; off = idx - 466944; }
      float4 v = *(const float4*)(src + (size_t)off * 4);
      ushort4 o;
      o.x = f2b(v.x); o.y = f2b(v.y); o.z = f2b(v.z); o.w = f2b(v.w);
      *(ushort4*)(dst + (size_t)off * 4) = o;
    }
  }
}

// ===== Stage 1: code GEMM [0,176) | LN [176,1456) ==========================
__global__ __launch_bounds__(256, 2) void k_s1(
    const float* __restrict__ ss, const float* __restrict__ rs,
    const float* __restrict__ g_s, const float* __restrict__ b_s,
    const float* __restrict__ g_r, const float* __restrict__ b_r,
    const float* __restrict__ codes, const u16* __restrict__ bw,
    float* __restrict__ s_ln, float* __restrict__ r_ln,
    float* __restrict__ cp) {
  __shared__ __align__(16) float SB[6400];
  int bid = blockIdx.x, t = threadIdx.x;
  if (bid < 176) {
    int nc = bid % 11, mb = bid / 11;
    int base = nc * 256;
    const u16* W; int N, colW;
    if (base < 768)       { W = bw;          N = DD;    colW = base; }
    else if (base < 1536) { W = bw + 294912; N = DD;    colW = base - 768; }
    else if (base < 2304) { W = bw + 589824; N = DD;    colW = base - 1536; }
    else                  { W = bw + 884736; N = INNER; colW = base - 2304; }
    int m0 = mb * 16;
#pragma unroll
    for (int p = 0; p < 24; p++) {
      int idx = p * 256 + t, r = idx / 384, k = idx % 384;
      SB[idx] = codes[(size_t)(m0 + r) * CDIM + k];
    }
    __syncthreads();
    int kl = t & 63, wid = t >> 6;
    const float* A0 = SB + (wid * 4) * 384;
    float4 a0 = {0,0,0,0}, a1 = {0,0,0,0}, a2 = {0,0,0,0}, a3 = {0,0,0,0};
    if (N == DD)
      gcoreb<384, DD>(A0, 384, W + colW + 4 * kl, a0, a1, a2, a3);
    else
      gcoreb<384, INNER>(A0, 384, W + colW + 4 * kl, a0, a1, a2, a3);
    int m = m0 + wid * 4, gcol = base + 4 * kl;
    *(float4*)(cp + (size_t)m * 2816 + gcol) = a0;
    *(float4*)(cp + (size_t)(m + 1) * 2816 + gcol) = a1;
    *(float4*)(cp + (size_t)(m + 2) * 2816 + gcol) = a2;
    *(float4*)(cp + (size_t)(m + 3) * 2816 + gcol) = a3;
  } else {
    int rr = bid - 176;
    const float *x, *g, *bb; float* y; int r;
    if (rr < 1024) { x = ss; g = g_s; bb = b_s; y = s_ln; r = rr; }
    else           { x = rs; g = g_r; bb = b_r; y = r_ln; r = rr - 1024; }
    const float* xr = x + (size_t)r * DD;
    float v0 = xr[t], v1 = xr[t + 256], v2 = xr[t + 512];
    float s = v0 + v1 + v2, sq = v0 * v0 + v1 * v1 + v2 * v2;
    for (int o = 32; o > 0; o >>= 1) {
      s += __shfl_down(s, o, 64); sq += __shfl_down(sq, o, 64);
    }
    int wid = t >> 6, lane = t & 63;
    if (lane == 0) { SB[wid] = s; SB[wid + 4] = sq; }
    __syncthreads();
    float sum = SB[0] + SB[1] + SB[2] + SB[3];
    float ssq = SB[4] + SB[5] + SB[6] + SB[7];
    float mu = sum * (1.0f / 768.0f);
    float var = ssq * (1.0f / 768.0f) - mu * mu;
    float rstd = rsqrtf(var + 1e-5f);
    float* yr = y + (size_t)r * DD;
    yr[t]       = (v0 - mu) * rstd * g[t]       + bb[t];
    yr[t + 256] = (v1 - mu) * rstd * g[t + 256] + bb[t + 256];
    yr[t + 512] = (v2 - mu) * rstd * g[t + 512] + bb[t + 512];
  }
}

// ===== Stage 2: q partial [0,128) (Kc=192, ks=4) | sT [128,320) ============
__global__ __launch_bounds__(256, 2) void k_s2(
    const float* __restrict__ s_ln, const float* __restrict__ r_ln,
    const float* __restrict__ cp, const u16* __restrict__ bw,
    float* __restrict__ sT, float* __restrict__ qp) {
  __shared__ __align__(16) float SB[4160];
  int bid = blockIdx.x, t = threadIdx.x;
  if (bid < 128) {
    int ks = bid & 3, t2 = bid >> 2, nc = t2 & 1, mb = t2 >> 1;
    int m0 = mb * 16, col0 = nc * 256, k0 = ks * 192;
#pragma unroll
    for (int p = 0; p < 12; p++) {
      int idx = p * 256 + t, r = idx / 192, k = idx % 192;
      int d = k0 + k;
      float mqv = cp[(size_t)(m0 + r) * 2816 + d] + 1.0f;
      SB[idx] = r_ln[(size_t)(m0 + r) * DD + d] * mqv;
    }
    __syncthreads();
    int kl = t & 63, wid = t >> 6;
    int col = col0 + 4 * kl;
    const float* A0 = SB + (wid * 4) * 192;
    float4 a0 = {0,0,0,0}, a1 = {0,0,0,0}, a2 = {0,0,0,0}, a3 = {0,0,0,0};
    gcoreb<192, INNER>(A0, 192, bw + 1081344 + (size_t)k0 * INNER + col,
                       a0, a1, a2, a3);
    int m = m0 + wid * 4;
    float* dst = qp + (size_t)ks * (256 * INNER);
    *(float4*)(dst + (size_t)m * INNER + col) = a0;
    *(float4*)(dst + (size_t)(m + 1) * INNER + col) = a1;
    *(float4*)(dst + (size_t)(m + 2) * INNER + col) = a2;
    *(float4*)(dst + (size_t)(m + 3) * INNER + col) = a3;
  } else {
    int tid = bid - 128;
    int vt = tid & 3, dt = (tid >> 2) % 12, b = tid / 48;
    int v0 = vt * 64, d0 = dt * 64;
    int j = t & 63, i0 = t >> 6;
#pragma unroll
    for (int p = 0; p < 16; p++) {
      int i = p * 4 + i0;
      SB[i * 65 + j] = s_ln[(size_t)(b * VV + v0 + i) * DD + d0 + j];
    }
    __syncthreads();
#pragma unroll
    for (int p = 0; p < 16; p++) {
      int i = p * 4 + i0;
      sT[((size_t)b * DD + d0 + i) * VV + v0 + j] = SB[j * 65 + i];
    }
  }
}

// ===== Stage 3: qmk [0,384) (K=64) | qbk [384,640) =========================
__global__ __launch_bounds__(256, 2) void k_s3(
    const float* __restrict__ qp, const float* __restrict__ bq,
    const u16* __restrict__ bw, const float* __restrict__ cp,
    const float* __restrict__ bk, float* __restrict__ qm,
    float* __restrict__ qbk) {
  __shared__ __align__(16) float SB[1024];
  int bid = blockIdx.x, t = threadIdx.x;
  if (bid < 384) {
    int h = bid & 7, dc = (bid >> 3) % 3, mb = bid / 24;
    int m0 = mb * 16;
#pragma unroll
    for (int p = 0; p < 4; p++) {
      int idx = p * 256 + t, r = idx >> 6, c = idx & 63;
      int i = h * HD + c;
      size_t off = (size_t)(m0 + r) * INNER + i;
      SB[idx] = qp[off] + qp[131072 + off] + qp[262144 + off] +
                qp[393216 + off] + bq[i];
    }
    __syncthreads();
    int kl = t & 63, wid = t >> 6;
    int col = dc * 256 + 4 * kl;
    const float* A0 = SB + (wid * 4) * HD;
    float4 a0 = {0,0,0,0}, a1 = {0,0,0,0}, a2 = {0,0,0,0}, a3 = {0,0,0,0};
    gcoreb<64, DD>(A0, HD, bw + 2260992 + (size_t)(h * HD) * DD + col,
                   a0, a1, a2, a3);
#pragma unroll
    for (int j = 0; j < 4; j++) {
      float4 a = (j == 0) ? a0 : (j == 1) ? a1 : (j == 2) ? a2 : a3;
      int m = m0 + wid * 4 + j;
      const float* mkp = cp + (size_t)m * 2816 + 768 + col;
      float4 o = {a.x * (mkp[0] + 1.0f), a.y * (mkp[1] + 1.0f),
                  a.z * (mkp[2] + 1.0f), a.w * (mkp[3] + 1.0f)};
      *(float4*)(qm + ((size_t)m * NH + h) * DD + col) = o;
    }
  } else {
    int m = bid - 384;
    size_t off = (size_t)m * INNER;
    SB[t] = (qp[off + t] + qp[131072 + off + t] + qp[262144 + off + t] +
             qp[393216 + off + t] + bq[t]) * bk[t];
    int t2 = t + 256;
    SB[t2] = (qp[off + t2] + qp[131072 + off + t2] + qp[262144 + off + t2] +
              qp[393216 + off + t2] + bq[t2]) * bk[t2];
    __syncthreads();
    if (t < 8) {
      float a = 0.f;
      for (int c = 0; c < HD; c++) a += SB[t * HD + c];
      qbk[m * NH + t] = a;
    }
  }
}

// ===== Stage 4: scores partial (512 blocks, Kc=192, ks=4) ==================
__global__ __launch_bounds__(256, 2) void k_s4(
    const float* __restrict__ qm, const float* __restrict__ sT,
    float* __restrict__ scp) {
  __shared__ __align__(16) float SB[3072];
  int bid = blockIdx.x, t = threadIdx.x;
  int ks = bid & 3, b = (bid >> 2) & 3, mb = bid >> 4;
  int gi0 = b * 512 + mb * 16, k0 = ks * 192;
#pragma unroll
  for (int p = 0; p < 12; p++) {
    int idx = p * 256 + t, r = idx / 192, k = idx % 192;
    SB[idx] = qm[(size_t)(gi0 + r) * DD + k0 + k];
  }
  __syncthreads();
  int kl = t & 63, wid = t >> 6;
  int col = 4 * kl;
  const float* A0 = SB + (wid * 4) * 192;
  float4 a0 = {0,0,0,0}, a1 = {0,0,0,0}, a2 = {0,0,0,0}, a3 = {0,0,0,0};
  gcore<192, VV>(A0, 192, sT + ((size_t)b * DD + k0) * VV + col, a0, a1, a2, a3);
  int gi = gi0 + wid * 4;
  float* dst = scp + (size_t)ks * (2048 * VV);
  *(float4*)(dst + (size_t)gi * VV + col) = a0;
  *(float4*)(dst + (size_t)(gi + 1) * VV + col) = a1;
  *(float4*)(dst + (size_t)(gi + 2) * VV + col) = a2;
  *(float4*)(dst + (size_t)(gi + 3) * VV + col) = a3;
}

// ===== Stage 5: softmax + ws GEMM (384 blocks, K=256) ======================
__global__ __launch_bounds__(256, 2) void k_s5(
    const float* __restrict__ scp, const float* __restrict__ qbk,
    const float* __restrict__ s_ln, const float* __restrict__ cp,
    float* __restrict__ wsm) {
  __shared__ __align__(16) float SB[4096];
  int bid = blockIdx.x, t = threadIdx.x;
  int dc = bid % 3, up = (bid / 3) % 32, b = bid / 96;
  int gi0 = b * 512 + up * 16;
#pragma unroll
  for (int p = 0; p < 16; p++) {
    int idx = p * 256 + t, r = idx >> 8, c = idx & 255;
    size_t o = (size_t)(gi0 + r) * VV + c;
    float v = scp[o] + scp[524288 + o] + scp[1048576 + o] + scp[1572864 + o];
    int m = b * 64 + up * 2 + (r >> 3), h = r & 7;
    SB[idx] = (v + qbk[m * NH + h]) * 0.125f;
  }
  __syncthreads();
  int wid = t >> 6, lane = t & 63;
#pragma unroll
  for (int j = 0; j < 4; j++) {
    int r = wid * 4 + j;
    float x0 = SB[r * 256 + lane],       x1 = SB[r * 256 + lane + 64];
    float x2 = SB[r * 256 + lane + 128], x3 = SB[r * 256 + lane + 192];
    float mx = fmaxf(fmaxf(x0, x1), fmaxf(x2, x3));
    for (int o = 1; o < 64; o <<= 1) mx = fmaxf(mx, __shfl_xor(mx, o, 64));
    float e0 = __expf(x0 - mx), e1 = __expf(x1 - mx);
    float e2 = __expf(x2 - mx), e3 = __expf(x3 - mx);
    float sm = e0 + e1 + e2 + e3;
    for (int o = 1; o < 64; o <<= 1) sm += __shfl_xor(sm, o, 64);
    float rinv = 1.0f / sm;
    SB[r * 256 + lane] = e0 * rinv;       SB[r * 256 + lane + 64] = e1 * rinv;
    SB[r * 256 + lane + 128] = e2 * rinv; SB[r * 256 + lane + 192] = e3 * rinv;
  }
  __syncthreads();
  int kl = t & 63;
  int col = dc * 256 + 4 * kl;
  const float* A0 = SB + (wid * 4) * 256;
  float4 a0 = {0,0,0,0}, a1 = {0,0,0,0}, a2 = {0,0,0,0}, a3 = {0,0,0,0};
  gcore<VV, DD>(A0, 256, s_ln + (size_t)(b * VV) * DD + col, a0, a1, a2, a3);
#pragma unroll
  for (int j = 0; j < 4; j++) {
    float4 a = (j == 0) ? a0 : (j == 1) ? a1 : (j == 2) ? a2 : a3;
    int r = wid * 4 + j;
    int ul = r >> 3, h = r & 7, m = b * 64 + up * 2 + ul;
    const float* mvp = cp + (size_t)m * 2816 + 1536 + col;
    float4 o = {a.x * (mvp[0] + 1.0f), a.y * (mvp[1] + 1.0f),
                a.z * (mvp[2] + 1.0f), a.w * (mvp[3] + 1.0f)};
    *(float4*)(wsm + ((size_t)h * 256 + m) * DD + col) = o;
  }
}

// ===== Stage 6: msg partial (256 blocks, Kc=96, ks=8) ======================
__global__ __launch_bounds__(256, 2) void k_s6(
    const float* __restrict__ wsm, const u16* __restrict__ bw,
    float* __restrict__ mmp) {
  __shared__ __align__(16) float SB[6400];
  int bid = blockIdx.x, t = threadIdx.x;
  int hp = bid & 1, ks = (bid >> 1) & 7, mb = bid >> 4;
  int h0 = hp * 4, m0 = mb * 16, k0 = ks * 96;
#pragma unroll
  for (int p = 0; p < 24; p++) {
    int idx = p * 256 + t;
    int e = idx / 1536, rem = idx % 1536, r = rem / 96, k = rem % 96;
    SB[e * 1540 + r * 96 + k] =
        wsm[((size_t)(h0 + e) * 256 + m0 + r) * DD + k0 + k];
  }
  __syncthreads();
  int kl = t & 63, wid = t >> 6;
  int hs = kl >> 4, c4 = 4 * (kl & 15);
  int colg = h0 * HD + hs * HD + c4;
  const float* A0 = SB + hs * 1540 + (wid * 4) * 96;
  float4 a0 = {0,0,0,0}, a1 = {0,0,0,0}, a2 = {0,0,0,0}, a3 = {0,0,0,0};
  gcoreb<96, INNER>(A0, 96, bw + 1474560 + (size_t)k0 * INNER + colg,
                    a0, a1, a2, a3);
  float* dst = mmp + (size_t)ks * (256 * INNER);
  int m = m0 + wid * 4;
  *(float4*)(dst + (size_t)m * INNER + colg) = a0;
  *(float4*)(dst + (size_t)(m + 1) * INNER + colg) = a1;
  *(float4*)(dst + (size_t)(m + 2) * INNER + colg) = a2;
  *(float4*)(dst + (size_t)(m + 3) * INNER + colg) = a3;
}

// ===== Stage 7: out partial (384 blocks, Kc=64, ks=8) ======================
__global__ __launch_bounds__(256, 2) void k_s7(
    const float* __restrict__ mmp, const float* __restrict__ bvv,
    const float* __restrict__ cp, const u16* __restrict__ bw,
    float* __restrict__ op) {
  __shared__ __align__(16) float SB[1024];
  int bid = blockIdx.x, t = threadIdx.x;
  int ks = bid & 7, dc = (bid >> 3) % 3, mb = bid / 24;
  int m0 = mb * 16, k0 = ks * 64;
#pragma unroll
  for (int p = 0; p < 4; p++) {
    int idx = p * 256 + t, r = idx >> 6, k = idx & 63;
    int i = k0 + k;
    size_t off = (size_t)(m0 + r) * INNER + i;
    float v = mmp[off] + mmp[131072 + off] + mmp[262144 + off] +
              mmp[393216 + off] + mmp[524288 + off] + mmp[655360 + off] +
              mmp[786432 + off] + mmp[917504 + off];
    float mev = cp[(size_t)(m0 + r) * 2816 + 2304 + i] + 1.0f;
    SB[idx] = (v + bvv[i]) * mev;
  }
  __syncthreads();
  int kl = t & 63, wid = t >> 6;
  int col = dc * 256 + 4 * kl;
  const float* A0 = SB + (wid * 4) * 64;
  float4 a0 = {0,0,0,0}, a1 = {0,0,0,0}, a2 = {0,0,0,0}, a3 = {0,0,0,0};
  gcoreb<64, DD>(A0, 64, bw + 1867776 + (size_t)k0 * DD + col, a0, a1, a2, a3);
  float* dst = op + (size_t)ks * (256 * DD);
  int m = m0 + wid * 4;
  *(float4*)(dst + (size_t)m * DD + col) = a0;
  *(float4*)(dst + (size_t)(m + 1) * DD + col) = a1;
  *(float4*)(dst + (size_t)(m + 2) * DD + col) = a2;
  *(float4*)(dst + (size_t)(m + 3) * DD + col) = a3;
}

// ===== Stage 8: epilogue (256 blocks) ======================================
__global__ __launch_bounds__(256) void k_s8(
    const float* __restrict__ op, const float* __restrict__ be,
    const float* __restrict__ gamma, const float* __restrict__ rs,
    float* __restrict__ outp) {
  int m = blockIdx.x, t = threadIdx.x;
#pragma unroll
  for (int j = 0; j < 3; j++) {
    int d = t + j * 256;
    size_t off = (size_t)m * DD + d;
    float v = op[off] + op[196608 + off] + op[393216 + off] +
              op[589824 + off] + op[786432 + off] + op[983040 + off] +
              op[1179648 + off] + op[1376256 + off];
    outp[off] = rs[off] + (v + be[d]) * gamma[d];
  }
}

extern "C" void kernel_launch(void* const* d_in, const int* in_sizes, int n_in,
                              void* d_out, int out_size, void* d_ws, size_t ws_size,
                              hipStream_t stream) {
  const float* rs     = (const float*)d_in[0];
  const float* codes  = (const float*)d_in[1];
  const float* ss     = (const float*)d_in[2];
  const float* ln_r_g = (const float*)d_in[3];
  const float* ln_r_b = (const float*)d_in[4];
  const float* ln_s_g = (const float*)d_in[5];
  const float* ln_s_b = (const float*)d_in[6];
  const float* Wq  = (const float*)d_in[7];
  const float* bq  = (const float*)d_in[8];
  const float* Wmq = (const float*)d_in[9];
  const float* Wk  = (const float*)d_in[10];
  const float* bk  = (const float*)d_in[11];
  const float* Wmk = (const float*)d_in[12];
  const float* Wv  = (const float*)d_in[13];
  const float* bv  = (const float*)d_in[14];
  const float* Wmv = (const float*)d_in[15];
  const float* We  = (const float*)d_in[16];
  const float* be  = (const float*)d_in[17];
  const float* Wme = (const float*)d_in[18];
  const float* gamma = (const float*)d_in[19];

  float* w = (float*)d_ws;
  // liveness-aliased layout (float offsets); peak ≈ 33.6 MB incl. bf16 bank
  float* s_ln = w;                  // 786432   (s1 -> s5)
  float* r_ln = w + 786432;         // 196608   (s1 -> s2)
  float* qp   = w + 1376256;        // 524288   (s2 -> s3, 4 partials)
  float* sT   = w + 1900544;        // 786432   (s2 -> s4)
  float* cp   = w + 2686976;        // 720896   (s1 -> s7) [m][2816]
  float* qbk  = w + 3407872;        // 2048     (s3 -> s5)
  float* qm   = w + 3409920;        // 1572864  (s3 -> s4)
  float* scp  = w + 4982784;        // 2097152  (s4 -> s5, 4 partials)
  float* wsm  = qm;                 // alias (s5 -> s6)
  float* mmp  = r_ln;               // alias r_ln..qp region (s6 -> s7, 8 partials)
  float* op   = scp;                // alias (s7 -> s8, 8 partials)
  u16*   bw   = (u16*)(w + 7079936); // 2654208 ushorts, bf16 weights (s0 -> s7)

  k_s0<<<dim3(1280), 256, 0, stream>>>(Wmq, Wmk, Wmv, Wme, Wq, Wk, Wv, We, bw);
  k_s1<<<dim3(1456), 256, 0, stream>>>(ss, rs, ln_s_g, ln_s_b, ln_r_g, ln_r_b,
                                       codes, bw, s_ln, r_ln, cp);
  k_s2<<<dim3(320), 256, 0, stream>>>(s_ln, r_ln, cp, bw, sT, qp);
  k_s3<<<dim3(640), 256, 0, stream>>>(qp, bq, bw, cp, bk, qm, qbk);
  k_s4<<<dim3(512), 256, 0, stream>>>(qm, sT, scp);
  k_s5<<<dim3(384), 256, 0, stream>>>(scp, qbk, s_ln, cp, wsm);
  k_s6<<<dim3(256), 256, 0, stream>>>(wsm, bw, mmp);
  k_s7<<<dim3(384), 256, 0, stream>>>(mmp, bv, cp, bw, op);
  k_s8<<<dim3(256), 256, 0, stream>>>(op, be, gamma, rs, (float*)d_out);
}